// Round 6
// baseline (2992.299 us; speedup 1.0000x reference)
//
#include <hip/hip_runtime.h>
#include <math.h>

#define NN 50000
#define NE 1600000
#define KORD 5
#define NB 196        // ceil(NN/256)
#define NCHUNK 64
#define ECHUNK (NE / NCHUNK)   // 25000
#define QTR 12500     // node quarter (k_deg)
#define MT 64         // epi node tile
#define NBK 782       // ceil(NN/64) destination buckets

// ---------------- deg: LDS-privatized weighted row histogram ----------------
__global__ __launch_bounds__(1024) void k_deg(const int* __restrict__ ei,
                                              const float* __restrict__ ew,
                                              float* __restrict__ deg_g) {
    __shared__ float h[QTR];   // 50 KB
    int q = blockIdx.x >> 6, ch = blockIdx.x & 63;
    for (int i = threadIdx.x; i < QTR; i += 1024) h[i] = 0.f;
    __syncthreads();
    int base = ch * ECHUNK, lo = q * QTR;
    for (int e = base + threadIdx.x; e < base + ECHUNK; e += 1024) {
        int li = ei[e] - lo;
        if ((unsigned)li < (unsigned)QTR) atomicAdd(&h[li], ew[e]);
    }
    __syncthreads();
    float* outp = deg_g + blockIdx.x * QTR;
    for (int i = threadIdx.x; i < QTR; i += 1024) outp[i] = h[i];
}

__global__ __launch_bounds__(256) void k_dis2(const float* __restrict__ deg_g,
                                              float* __restrict__ dis) {
    int n = blockIdx.x * 256 + threadIdx.x;
    if (n >= NN) return;
    int q = n / QTR, i = n % QTR;
    const float* p = deg_g + (q * 64) * QTR + i;
    float s = 0.f;
#pragma unroll
    for (int c = 0; c < 64; c++) s += p[c * QTR];
    dis[n] = s > 0.f ? rsqrtf(fmaxf(s, 1e-30f)) : 0.f;
}

// ---------------- coarse bucket histogram: bh[bucket][chunk] ----------------
__global__ __launch_bounds__(1024) void k_bhist(const int* __restrict__ ei,
                                                int* __restrict__ bh) {
    __shared__ int hist[NBK];
    int ch = blockIdx.x;
    for (int i = threadIdx.x; i < NBK; i += 1024) hist[i] = 0;
    __syncthreads();
    const int* cols = ei + NE;
    int base = ch * ECHUNK;
    for (int e = base + threadIdx.x; e < base + ECHUNK; e += 1024)
        atomicAdd(&hist[cols[e] >> 6], 1);
    __syncthreads();
    for (int b = threadIdx.x; b < NBK; b += 1024) bh[b * 64 + ch] = hist[b];
}

// one block: bucket totals -> exclusive scan -> off_bk; bh becomes cursors
__global__ __launch_bounds__(1024) void k_bscan(int* __restrict__ bh,
                                                int* __restrict__ off_bk) {
    __shared__ int s[1024];
    int t = threadIdx.x;
    int vals[64];
    int tot = 0;
    if (t < NBK) {
        const int4* p = (const int4*)(bh + t * 64);
#pragma unroll
        for (int i = 0; i < 16; i++) {
            int4 q = p[i];
            vals[i * 4 + 0] = q.x; vals[i * 4 + 1] = q.y;
            vals[i * 4 + 2] = q.z; vals[i * 4 + 3] = q.w;
            tot += q.x + q.y + q.z + q.w;
        }
    }
    s[t] = (t < NBK) ? tot : 0;
    __syncthreads();
    for (int d = 1; d < 1024; d <<= 1) {
        int u = (t >= d) ? s[t - d] : 0;
        __syncthreads();
        s[t] += u;
        __syncthreads();
    }
    if (t < NBK) {
        int run = (t == 0) ? 0 : s[t - 1];
        off_bk[t] = run;
        int4* p = (int4*)(bh + t * 64);
#pragma unroll
        for (int i = 0; i < 16; i++) {
            int4 q;
            q.x = run; run += vals[i * 4 + 0];
            q.y = run; run += vals[i * 4 + 1];
            q.z = run; run += vals[i * 4 + 2];
            q.w = run; run += vals[i * 4 + 3];
            p[i] = q;
        }
    }
    if (t == 0) off_bk[NBK] = NE;
}

// coarse permute: bucket edges by c>>6; record = (r | c<<16, weight-bits)
__global__ __launch_bounds__(1024) void k_cperm(const int* __restrict__ ei,
                                                const float* __restrict__ ew,
                                                const float* __restrict__ dis,
                                                const int* __restrict__ bh,
                                                int2* __restrict__ edges) {
    __shared__ int cur[NBK];
    int ch = blockIdx.x;
    for (int b = threadIdx.x; b < NBK; b += 1024) cur[b] = bh[b * 64 + ch];
    __syncthreads();
    int base = ch * ECHUNK;
    for (int e = base + threadIdx.x; e < base + ECHUNK; e += 1024) {
        int r = ei[e], c = ei[NE + e];
        float w = -dis[r] * ew[e] * dis[c];
        int pos = atomicAdd(&cur[c >> 6], 1);
        edges[pos] = make_int2(r | (c << 16), __float_as_int(w));
    }
}

// ---------------- spmm: bucketed LDS-scatter ----------------
// block = 64-node bucket; 8 lanes/edge (float4 each); LDS fp32 atomics;
// flush folds Chebyshev: out = scale*acc - prev.
__global__ __launch_bounds__(256) void k_spmm(const int* __restrict__ off_bk,
                                              const int2* __restrict__ edges,
                                              const float* __restrict__ vin,
                                              const float* __restrict__ prev,
                                              float* __restrict__ vout,
                                              float scale) {
    __shared__ float acc[64][33];  // pad 33: bank = (cl + 4*sub + k) % 32
    int b = blockIdx.x;
    for (int i = threadIdx.x; i < 64 * 33; i += 256) (&acc[0][0])[i] = 0.f;
    __syncthreads();
    int e0 = off_bk[b], e1 = off_bk[b + 1];
    int group = threadIdx.x >> 3, sub = threadIdx.x & 7;
    int base = b << 6;
    const float4* vin4 = (const float4*)vin;
    int i = e0 + group;
    for (; i + 32 < e1; i += 64) {  // 2 independent edges in flight per lane
        int2 ea = edges[i];
        int2 eb = edges[i + 32];
        unsigned ra = (unsigned)ea.x, rb = (unsigned)eb.x;
        float4 va = vin4[(ra & 0xffffu) * 8 + sub];
        float4 vb = vin4[(rb & 0xffffu) * 8 + sub];
        float wa = __int_as_float(ea.y), wb = __int_as_float(eb.y);
        float* aa = &acc[(ra >> 16) - base][sub * 4];
        float* ab = &acc[(rb >> 16) - base][sub * 4];
        atomicAdd(aa + 0, wa * va.x); atomicAdd(aa + 1, wa * va.y);
        atomicAdd(aa + 2, wa * va.z); atomicAdd(aa + 3, wa * va.w);
        atomicAdd(ab + 0, wb * vb.x); atomicAdd(ab + 1, wb * vb.y);
        atomicAdd(ab + 2, wb * vb.z); atomicAdd(ab + 3, wb * vb.w);
    }
    if (i < e1) {
        int2 ea = edges[i];
        unsigned ra = (unsigned)ea.x;
        float4 va = vin4[(ra & 0xffffu) * 8 + sub];
        float wa = __int_as_float(ea.y);
        float* aa = &acc[(ra >> 16) - base][sub * 4];
        atomicAdd(aa + 0, wa * va.x); atomicAdd(aa + 1, wa * va.y);
        atomicAdd(aa + 2, wa * va.z); atomicAdd(aa + 3, wa * va.w);
    }
    __syncthreads();
    for (int idx = threadIdx.x; idx < 64 * 8; idx += 256) {
        int nl = idx >> 3, s4 = idx & 7;
        int n = base + nl;
        if (n < NN) {
            const float* a = &acc[nl][s4 * 4];
            float4 o;
            if (prev) {
                float4 p = ((const float4*)prev)[n * 8 + s4];
                o = make_float4(fmaf(scale, a[0], -p.x), fmaf(scale, a[1], -p.y),
                                fmaf(scale, a[2], -p.z), fmaf(scale, a[3], -p.w));
            } else {
                o = make_float4(a[0], a[1], a[2], a[3]);
            }
            ((float4*)vout)[n * 8 + s4] = o;
        }
    }
}

// ---------------- epi1: LDS-tiled GEMM (K=160 -> 32z+32h) + GRU fuse --------
__global__ __launch_bounds__(256) void k_epi1(
    const float* __restrict__ x, const float* __restrict__ t1,
    const float* __restrict__ t2, const float* __restrict__ t3,
    const float* __restrict__ t4, const float* __restrict__ Wx1,
    const float* __restrict__ bx1, const float* __restrict__ bh1,
    float* __restrict__ h) {
    __shared__ float T[5][MT][33];
    int n0 = blockIdx.x * MT;
    const float* bufs[5] = {x, t1, t2, t3, t4};
#pragma unroll
    for (int b = 0; b < 5; b++) {
        for (int idx = threadIdx.x; idx < MT * 8; idx += 256) {
            int r = idx >> 3, c4 = idx & 7;
            int rr = n0 + r; if (rr >= NN) rr = NN - 1;
            float4 v = *(const float4*)(bufs[b] + rr * 32 + c4 * 4);
            float* dst = &T[b][r][c4 * 4];
            dst[0] = v.x; dst[1] = v.y; dst[2] = v.z; dst[3] = v.w;
        }
    }
    __syncthreads();
    int nq = threadIdx.x & 15, oq = threadIdx.x >> 4;
    int ob = oq * 2;
    const float* Wz = Wx1;
    const float* Wh = Wx1 + 2 * KORD * 32 * 32;
    float az_[4][2] = {{0.f}}, ah_[4][2] = {{0.f}};
#pragma unroll
    for (int b = 0; b < 5; b++) {
#pragma unroll 4
        for (int i = 0; i < 32; i++) {
            int kw = b * 1024 + i * 32 + ob;
            float wz0 = Wz[kw], wz1 = Wz[kw + 1];
            float wh0 = Wh[kw], wh1 = Wh[kw + 1];
#pragma unroll
            for (int a = 0; a < 4; a++) {
                float tx = T[b][nq + 16 * a][i];
                az_[a][0] = fmaf(tx, wz0, az_[a][0]);
                az_[a][1] = fmaf(tx, wz1, az_[a][1]);
                ah_[a][0] = fmaf(tx, wh0, ah_[a][0]);
                ah_[a][1] = fmaf(tx, wh1, ah_[a][1]);
            }
        }
    }
#pragma unroll
    for (int a = 0; a < 4; a++) {
        int n = n0 + nq + 16 * a;
        if (n < NN) {
#pragma unroll
            for (int c = 0; c < 2; c++) {
                int j = ob + c;
                float zz = az_[a][c] + bx1[j] + bh1[j];
                float hh = ah_[a][c] + bx1[64 + j] + bh1[64 + j];
                float z = 1.f / (1.f + __expf(-zz));
                float tt = __expf(-2.f * fabsf(hh));
                float ht = copysignf((1.f - tt) / (1.f + tt), hh);
                h[n * 32 + j] = fmaxf((1.f - z) * ht, 0.f);
            }
        }
    }
}

// ---------------- epi2: LDS-tiled GEMM (K=160 -> 16z+16h) + final linear ----
__global__ __launch_bounds__(256) void k_epi2(
    const float* __restrict__ hin, const float* __restrict__ t1,
    const float* __restrict__ t2, const float* __restrict__ t3,
    const float* __restrict__ t4, const float* __restrict__ Wx2,
    const float* __restrict__ bx2, const float* __restrict__ bh2,
    const float* __restrict__ Wl, const float* __restrict__ bl,
    float* __restrict__ out) {
    __shared__ float T[5][MT][33];
    __shared__ float H2[MT][17];
    int n0 = blockIdx.x * MT;
    const float* bufs[5] = {hin, t1, t2, t3, t4};
#pragma unroll
    for (int b = 0; b < 5; b++) {
        for (int idx = threadIdx.x; idx < MT * 8; idx += 256) {
            int r = idx >> 3, c4 = idx & 7;
            int rr = n0 + r; if (rr >= NN) rr = NN - 1;
            float4 v = *(const float4*)(bufs[b] + rr * 32 + c4 * 4);
            float* dst = &T[b][r][c4 * 4];
            dst[0] = v.x; dst[1] = v.y; dst[2] = v.z; dst[3] = v.w;
        }
    }
    __syncthreads();
    int nq = threadIdx.x & 15, j = threadIdx.x >> 4;
    const float* Wz = Wx2;
    const float* Wh = Wx2 + 2 * KORD * 32 * 16;
    float az_[4] = {0.f}, ah_[4] = {0.f};
#pragma unroll
    for (int b = 0; b < 5; b++) {
#pragma unroll 4
        for (int i = 0; i < 32; i++) {
            int kw = b * 512 + i * 16 + j;
            float wz0 = Wz[kw], wh0 = Wh[kw];
#pragma unroll
            for (int a = 0; a < 4; a++) {
                float tx = T[b][nq + 16 * a][i];
                az_[a] = fmaf(tx, wz0, az_[a]);
                ah_[a] = fmaf(tx, wh0, ah_[a]);
            }
        }
    }
#pragma unroll
    for (int a = 0; a < 4; a++) {
        float zz = az_[a] + bx2[j] + bh2[j];
        float hh = ah_[a] + bx2[32 + j] + bh2[32 + j];
        float z = 1.f / (1.f + __expf(-zz));
        float tt = __expf(-2.f * fabsf(hh));
        float ht = copysignf((1.f - tt) / (1.f + tt), hh);
        H2[nq + 16 * a][j] = fmaxf((1.f - z) * ht, 0.f);
    }
    __syncthreads();
    for (int idx = threadIdx.x; idx < MT * 12; idx += 256) {
        int n = idx / 12, p = idx % 12;
        int gn = n0 + n;
        if (gn < NN) {
            float o = bl[p];
#pragma unroll
            for (int jj = 0; jj < 16; jj++) o = fmaf(H2[n][jj], Wl[p * 16 + jj], o);
            out[gn * 12 + p] = o;
        }
    }
}

// ---------------- launch ----------------

extern "C" void kernel_launch(void* const* d_in, const int* in_sizes, int n_in,
                              void* d_out, int out_size, void* d_ws, size_t ws_size,
                              hipStream_t stream) {
    const float* x   = (const float*)d_in[0];
    const int*   ei  = (const int*)d_in[1];
    const float* ew  = (const float*)d_in[2];
    const float* Wx1 = (const float*)d_in[3];
    const float* bx1 = (const float*)d_in[4];
    const float* bh1 = (const float*)d_in[6];
    const float* Wx2 = (const float*)d_in[7];
    const float* bx2 = (const float*)d_in[8];
    const float* bh2 = (const float*)d_in[10];
    const float* Wl  = (const float*)d_in[11];
    const float* bl  = (const float*)d_in[12];
    float* out = (float*)d_out;

    float* ws    = (float*)d_ws;
    float* dis   = ws;                        // NN floats (pad to 50048)
    int*   bh    = (int*)(ws + 50048);        // NBK*64 = 50048 ints
    int*   off_bk= bh + 50048;                // NBK+1 ints (pad 800)
    int2*  edges = (int2*)(off_bk + 800);     // NE int2
    float* T1    = (float*)(edges + NE);      // NN*32 floats each
    float* T2    = T1 + NN * 32;
    float* T3    = T2 + NN * 32;
    float* T4    = T3 + NN * 32;
    float* hb    = T4 + NN * 32;
    float* deg_g = T1;  // 256*QTR floats (T1+T2 region, dead before spmm)

    k_deg  <<<256, 1024, 0, stream>>>(ei, ew, deg_g);
    k_dis2 <<<NB, 256, 0, stream>>>(deg_g, dis);
    k_bhist<<<NCHUNK, 1024, 0, stream>>>(ei, bh);
    k_bscan<<<1, 1024, 0, stream>>>(bh, off_bk);
    k_cperm<<<NCHUNK, 1024, 0, stream>>>(ei, ew, dis, bh, edges);

    // ---- cell 1: v = x ----
    k_spmm<<<NBK, 256, 0, stream>>>(off_bk, edges, x,  nullptr, T1, 1.f);
    k_spmm<<<NBK, 256, 0, stream>>>(off_bk, edges, T1, x,       T2, 2.f);
    k_spmm<<<NBK, 256, 0, stream>>>(off_bk, edges, T2, T1,      T3, 2.f);
    k_spmm<<<NBK, 256, 0, stream>>>(off_bk, edges, T3, T2,      T4, 2.f);
    k_epi1<<<NBK, 256, 0, stream>>>(x, T1, T2, T3, T4, Wx1, bx1, bh1, hb);

    // ---- cell 2: v = hb ----
    k_spmm<<<NBK, 256, 0, stream>>>(off_bk, edges, hb, nullptr, T1, 1.f);
    k_spmm<<<NBK, 256, 0, stream>>>(off_bk, edges, T1, hb,      T2, 2.f);
    k_spmm<<<NBK, 256, 0, stream>>>(off_bk, edges, T2, T1,      T3, 2.f);
    k_spmm<<<NBK, 256, 0, stream>>>(off_bk, edges, T3, T2,      T4, 2.f);
    k_epi2<<<NBK, 256, 0, stream>>>(hb, T1, T2, T3, T4, Wx2, bx2, bh2, Wl, bl, out);
}

// Round 7
// 478.258 us; speedup vs baseline: 6.2567x; 6.2567x over previous
//
#include <hip/hip_runtime.h>
#include <math.h>

#define NN 50000
#define NE 1600000
#define KORD 5
#define NB 196          // ceil(NN/256)
#define QTR 12500       // node quarter (k_deg)
#define MT 64           // epi node tile
#define NBK 782         // ceil(NN/64) destination buckets
#define NBP 800         // padded bucket stride
#define NCH 128         // chunks for bucket kernels
#define ECH (NE / NCH)  // 12500
#define EC4 (NE / 64)   // 25000 (k_deg chunks)

#define SCALE_W 2097152.0f          // 2^21 spmm fixed point
#define INV_SCALE_W (1.0f / 2097152.0f)
#define SCALE_D 4194304.0f          // 2^22 degree fixed point
#define INV_SCALE_D (1.0f / 4194304.0f)

// ---------------- deg: LDS int-fixed-point weighted row histogram ----------
__global__ __launch_bounds__(1024) void k_deg(const int* __restrict__ ei,
                                              const float* __restrict__ ew,
                                              int* __restrict__ deg_g) {
    __shared__ int h[QTR];   // 50 KB
    int q = blockIdx.x >> 6, ch = blockIdx.x & 63;
    for (int i = threadIdx.x; i < QTR; i += 1024) h[i] = 0;
    __syncthreads();
    int base = ch * EC4, lo = q * QTR;
    for (int e = base + threadIdx.x; e < base + EC4; e += 1024) {
        int li = ei[e] - lo;
        if ((unsigned)li < (unsigned)QTR)
            atomicAdd(&h[li], __float2int_rn(ew[e] * SCALE_D));  // ds_add_u32
    }
    __syncthreads();
    int* outp = deg_g + blockIdx.x * QTR;
    for (int i = threadIdx.x; i < QTR; i += 1024) outp[i] = h[i];
}

__global__ __launch_bounds__(256) void k_dis2(const int* __restrict__ deg_g,
                                              float* __restrict__ dis) {
    int n = blockIdx.x * 256 + threadIdx.x;
    if (n >= NN) return;
    int q = n / QTR, i = n % QTR;
    const int* p = deg_g + (q * 64) * QTR + i;
    int s = 0;
#pragma unroll
    for (int c = 0; c < 64; c++) s += p[c * QTR];
    float d = (float)s * INV_SCALE_D;
    dis[n] = s > 0 ? rsqrtf(fmaxf(d, 1e-30f)) : 0.f;
}

// ---------------- bucket histogram: bh[ch][b] (transposed layout) ----------
__global__ __launch_bounds__(1024) void k_bhist(const int* __restrict__ ei,
                                                int* __restrict__ bh) {
    __shared__ int hist[NBK];
    int ch = blockIdx.x;
    for (int i = threadIdx.x; i < NBK; i += 1024) hist[i] = 0;
    __syncthreads();
    const int* cols = ei + NE;
    int base = ch * ECH;
    for (int e = base + threadIdx.x; e < base + ECH; e += 1024)
        atomicAdd(&hist[cols[e] >> 6], 1);
    __syncthreads();
    int* outp = bh + ch * NBP;
    for (int b = threadIdx.x; b < NBK; b += 1024) outp[b] = hist[b];
}

// bucket totals across chunks (coalesced: consecutive b)
__global__ __launch_bounds__(256) void k_btot(const int* __restrict__ bh,
                                              int* __restrict__ tot) {
    int b = blockIdx.x * 256 + threadIdx.x;
    if (b >= NBK) return;
    int s = 0;
#pragma unroll 8
    for (int ch = 0; ch < NCH; ch++) s += bh[ch * NBP + b];
    tot[b] = s;
}

// tiny one-block scan of 782 totals -> off_bk
__global__ __launch_bounds__(1024) void k_bscan1(const int* __restrict__ tot,
                                                 int* __restrict__ off_bk) {
    __shared__ int s[1024];
    int t = threadIdx.x;
    s[t] = (t < NBK) ? tot[t] : 0;
    __syncthreads();
    for (int d = 1; d < 1024; d <<= 1) {
        int u = (t >= d) ? s[t - d] : 0;
        __syncthreads();
        s[t] += u;
        __syncthreads();
    }
    if (t < NBK) off_bk[t] = (t == 0) ? 0 : s[t - 1];
    if (t == 0) off_bk[NBK] = NE;
}

// per-(chunk,bucket) absolute cursors written back into bh (coalesced in b)
__global__ __launch_bounds__(256) void k_bcur(int* __restrict__ bh,
                                              const int* __restrict__ off_bk) {
    int b = blockIdx.x * 256 + threadIdx.x;
    if (b >= NBK) return;
    int run = off_bk[b];
    for (int ch = 0; ch < NCH; ch++) {
        int v = bh[ch * NBP + b];
        bh[ch * NBP + b] = run;
        run += v;
    }
}

// coarse permute: record = (r | local_c<<16, weight-bits); dense-ish writes
__global__ __launch_bounds__(1024) void k_cperm(const int* __restrict__ ei,
                                                const float* __restrict__ ew,
                                                const float* __restrict__ dis,
                                                const int* __restrict__ bh,
                                                int2* __restrict__ edges) {
    __shared__ int cur[NBK];
    int ch = blockIdx.x;
    const int* cp = bh + ch * NBP;
    for (int b = threadIdx.x; b < NBK; b += 1024) cur[b] = cp[b];
    __syncthreads();
    int base = ch * ECH;
    for (int e = base + threadIdx.x; e < base + ECH; e += 1024) {
        int r = ei[e], c = ei[NE + e];
        float w = -dis[r] * ew[e] * dis[c];
        int pos = atomicAdd(&cur[c >> 6], 1);   // ds_add_u32, native
        int packed = (int)((unsigned)r | ((unsigned)(c & 63) << 16));
        edges[pos] = make_int2(packed, __float_as_int(w));
    }
}

// ---------------- spmm: bucketed LDS-scatter, int fixed-point atomics ------
// block = 64-node bucket; 8 lanes/edge (float4 each); ds_add_u32 (native).
__global__ __launch_bounds__(256) void k_spmm(const int* __restrict__ off_bk,
                                              const int2* __restrict__ edges,
                                              const float* __restrict__ vin,
                                              const float* __restrict__ prev,
                                              float* __restrict__ vout,
                                              float scale) {
    __shared__ int acc[64][33];  // pad 33 breaks stride-32 banking
    int b = blockIdx.x;
    for (int i = threadIdx.x; i < 64 * 33; i += 256) (&acc[0][0])[i] = 0;
    __syncthreads();
    int e0 = off_bk[b], e1 = off_bk[b + 1];
    int group = threadIdx.x >> 3, sub = threadIdx.x & 7;
    const float4* vin4 = (const float4*)vin;
    int i = e0 + group;
    for (; i + 32 < e1; i += 64) {  // 2 independent edges in flight per lane
        int2 ea = edges[i];
        int2 eb = edges[i + 32];
        unsigned ra = (unsigned)ea.x, rb = (unsigned)eb.x;
        float4 va = vin4[(ra & 0xffffu) * 8 + sub];
        float4 vb = vin4[(rb & 0xffffu) * 8 + sub];
        float wa = __int_as_float(ea.y) * SCALE_W;
        float wb = __int_as_float(eb.y) * SCALE_W;
        int* aa = &acc[ra >> 16][sub * 4];
        int* ab = &acc[rb >> 16][sub * 4];
        atomicAdd(aa + 0, __float2int_rn(wa * va.x));
        atomicAdd(aa + 1, __float2int_rn(wa * va.y));
        atomicAdd(aa + 2, __float2int_rn(wa * va.z));
        atomicAdd(aa + 3, __float2int_rn(wa * va.w));
        atomicAdd(ab + 0, __float2int_rn(wb * vb.x));
        atomicAdd(ab + 1, __float2int_rn(wb * vb.y));
        atomicAdd(ab + 2, __float2int_rn(wb * vb.z));
        atomicAdd(ab + 3, __float2int_rn(wb * vb.w));
    }
    if (i < e1) {
        int2 ea = edges[i];
        unsigned ra = (unsigned)ea.x;
        float4 va = vin4[(ra & 0xffffu) * 8 + sub];
        float wa = __int_as_float(ea.y) * SCALE_W;
        int* aa = &acc[ra >> 16][sub * 4];
        atomicAdd(aa + 0, __float2int_rn(wa * va.x));
        atomicAdd(aa + 1, __float2int_rn(wa * va.y));
        atomicAdd(aa + 2, __float2int_rn(wa * va.z));
        atomicAdd(aa + 3, __float2int_rn(wa * va.w));
    }
    __syncthreads();
    float sf = scale * INV_SCALE_W;
    int base = b << 6;
    for (int idx = threadIdx.x; idx < 64 * 8; idx += 256) {
        int nl = idx >> 3, s4 = idx & 7;
        int n = base + nl;
        if (n < NN) {
            const int* a = &acc[nl][s4 * 4];
            float4 o;
            if (prev) {
                float4 p = ((const float4*)prev)[n * 8 + s4];
                o = make_float4(fmaf(sf, (float)a[0], -p.x),
                                fmaf(sf, (float)a[1], -p.y),
                                fmaf(sf, (float)a[2], -p.z),
                                fmaf(sf, (float)a[3], -p.w));
            } else {
                o = make_float4(sf * (float)a[0], sf * (float)a[1],
                                sf * (float)a[2], sf * (float)a[3]);
            }
            ((float4*)vout)[n * 8 + s4] = o;
        }
    }
}

// ---------------- epi1: LDS-tiled GEMM (K=160 -> 32z+32h) + GRU fuse --------
__global__ __launch_bounds__(256) void k_epi1(
    const float* __restrict__ x, const float* __restrict__ t1,
    const float* __restrict__ t2, const float* __restrict__ t3,
    const float* __restrict__ t4, const float* __restrict__ Wx1,
    const float* __restrict__ bx1, const float* __restrict__ bh1,
    float* __restrict__ h) {
    __shared__ float T[5][MT][33];
    int n0 = blockIdx.x * MT;
    const float* bufs[5] = {x, t1, t2, t3, t4};
#pragma unroll
    for (int b = 0; b < 5; b++) {
        for (int idx = threadIdx.x; idx < MT * 8; idx += 256) {
            int r = idx >> 3, c4 = idx & 7;
            int rr = n0 + r; if (rr >= NN) rr = NN - 1;
            float4 v = *(const float4*)(bufs[b] + rr * 32 + c4 * 4);
            float* dst = &T[b][r][c4 * 4];
            dst[0] = v.x; dst[1] = v.y; dst[2] = v.z; dst[3] = v.w;
        }
    }
    __syncthreads();
    int nq = threadIdx.x & 15, oq = threadIdx.x >> 4;
    int ob = oq * 2;
    const float* Wz = Wx1;
    const float* Wh = Wx1 + 2 * KORD * 32 * 32;
    float az_[4][2] = {{0.f}}, ah_[4][2] = {{0.f}};
#pragma unroll
    for (int b = 0; b < 5; b++) {
#pragma unroll 4
        for (int i = 0; i < 32; i++) {
            int kw = b * 1024 + i * 32 + ob;
            float wz0 = Wz[kw], wz1 = Wz[kw + 1];
            float wh0 = Wh[kw], wh1 = Wh[kw + 1];
#pragma unroll
            for (int a = 0; a < 4; a++) {
                float tx = T[b][nq + 16 * a][i];
                az_[a][0] = fmaf(tx, wz0, az_[a][0]);
                az_[a][1] = fmaf(tx, wz1, az_[a][1]);
                ah_[a][0] = fmaf(tx, wh0, ah_[a][0]);
                ah_[a][1] = fmaf(tx, wh1, ah_[a][1]);
            }
        }
    }
#pragma unroll
    for (int a = 0; a < 4; a++) {
        int n = n0 + nq + 16 * a;
        if (n < NN) {
#pragma unroll
            for (int c = 0; c < 2; c++) {
                int j = ob + c;
                float zz = az_[a][c] + bx1[j] + bh1[j];
                float hh = ah_[a][c] + bx1[64 + j] + bh1[64 + j];
                float z = 1.f / (1.f + __expf(-zz));
                float tt = __expf(-2.f * fabsf(hh));
                float ht = copysignf((1.f - tt) / (1.f + tt), hh);
                h[n * 32 + j] = fmaxf((1.f - z) * ht, 0.f);
            }
        }
    }
}

// ---------------- epi2: LDS-tiled GEMM (K=160 -> 16z+16h) + final linear ----
__global__ __launch_bounds__(256) void k_epi2(
    const float* __restrict__ hin, const float* __restrict__ t1,
    const float* __restrict__ t2, const float* __restrict__ t3,
    const float* __restrict__ t4, const float* __restrict__ Wx2,
    const float* __restrict__ bx2, const float* __restrict__ bh2,
    const float* __restrict__ Wl, const float* __restrict__ bl,
    float* __restrict__ out) {
    __shared__ float T[5][MT][33];
    __shared__ float H2[MT][17];
    int n0 = blockIdx.x * MT;
    const float* bufs[5] = {hin, t1, t2, t3, t4};
#pragma unroll
    for (int b = 0; b < 5; b++) {
        for (int idx = threadIdx.x; idx < MT * 8; idx += 256) {
            int r = idx >> 3, c4 = idx & 7;
            int rr = n0 + r; if (rr >= NN) rr = NN - 1;
            float4 v = *(const float4*)(bufs[b] + rr * 32 + c4 * 4);
            float* dst = &T[b][r][c4 * 4];
            dst[0] = v.x; dst[1] = v.y; dst[2] = v.z; dst[3] = v.w;
        }
    }
    __syncthreads();
    int nq = threadIdx.x & 15, j = threadIdx.x >> 4;
    const float* Wz = Wx2;
    const float* Wh = Wx2 + 2 * KORD * 32 * 16;
    float az_[4] = {0.f}, ah_[4] = {0.f};
#pragma unroll
    for (int b = 0; b < 5; b++) {
#pragma unroll 4
        for (int i = 0; i < 32; i++) {
            int kw = b * 512 + i * 16 + j;
            float wz0 = Wz[kw], wh0 = Wh[kw];
#pragma unroll
            for (int a = 0; a < 4; a++) {
                float tx = T[b][nq + 16 * a][i];
                az_[a] = fmaf(tx, wz0, az_[a]);
                ah_[a] = fmaf(tx, wh0, ah_[a]);
            }
        }
    }
#pragma unroll
    for (int a = 0; a < 4; a++) {
        float zz = az_[a] + bx2[j] + bh2[j];
        float hh = ah_[a] + bx2[32 + j] + bh2[32 + j];
        float z = 1.f / (1.f + __expf(-zz));
        float tt = __expf(-2.f * fabsf(hh));
        float ht = copysignf((1.f - tt) / (1.f + tt), hh);
        H2[nq + 16 * a][j] = fmaxf((1.f - z) * ht, 0.f);
    }
    __syncthreads();
    for (int idx = threadIdx.x; idx < MT * 12; idx += 256) {
        int n = idx / 12, p = idx % 12;
        int gn = n0 + n;
        if (gn < NN) {
            float o = bl[p];
#pragma unroll
            for (int jj = 0; jj < 16; jj++) o = fmaf(H2[n][jj], Wl[p * 16 + jj], o);
            out[gn * 12 + p] = o;
        }
    }
}

// ---------------- launch ----------------

extern "C" void kernel_launch(void* const* d_in, const int* in_sizes, int n_in,
                              void* d_out, int out_size, void* d_ws, size_t ws_size,
                              hipStream_t stream) {
    const float* x   = (const float*)d_in[0];
    const int*   ei  = (const int*)d_in[1];
    const float* ew  = (const float*)d_in[2];
    const float* Wx1 = (const float*)d_in[3];
    const float* bx1 = (const float*)d_in[4];
    const float* bh1 = (const float*)d_in[6];
    const float* Wx2 = (const float*)d_in[7];
    const float* bx2 = (const float*)d_in[8];
    const float* bh2 = (const float*)d_in[10];
    const float* Wl  = (const float*)d_in[11];
    const float* bl  = (const float*)d_in[12];
    float* out = (float*)d_out;

    float* ws     = (float*)d_ws;
    float* dis    = ws;                         // 50048 floats
    int*   bh     = (int*)(ws + 50048);         // NCH*NBP = 102400 ints
    int*   tot    = bh + NCH * NBP;             // 800 ints
    int*   off_bk = tot + 800;                  // 800 ints
    int2*  edges  = (int2*)(off_bk + 800);      // NE int2
    float* T1     = (float*)(edges + NE);       // NN*32 floats each
    float* T2     = T1 + NN * 32;
    float* T3     = T2 + NN * 32;
    float* T4     = T3 + NN * 32;
    float* hb     = T4 + NN * 32;
    int*   deg_g  = (int*)T1;  // 256*QTR ints (T1+T2 region, dead before spmm)

    k_deg  <<<256, 1024, 0, stream>>>(ei, ew, deg_g);
    k_dis2 <<<NB, 256, 0, stream>>>(deg_g, dis);
    k_bhist<<<NCH, 1024, 0, stream>>>(ei, bh);
    k_btot <<<4, 256, 0, stream>>>(bh, tot);
    k_bscan1<<<1, 1024, 0, stream>>>(tot, off_bk);
    k_bcur <<<4, 256, 0, stream>>>(bh, off_bk);
    k_cperm<<<NCH, 1024, 0, stream>>>(ei, ew, dis, bh, edges);

    // ---- cell 1: v = x ----
    k_spmm<<<NBK, 256, 0, stream>>>(off_bk, edges, x,  nullptr, T1, 1.f);
    k_spmm<<<NBK, 256, 0, stream>>>(off_bk, edges, T1, x,       T2, 2.f);
    k_spmm<<<NBK, 256, 0, stream>>>(off_bk, edges, T2, T1,      T3, 2.f);
    k_spmm<<<NBK, 256, 0, stream>>>(off_bk, edges, T3, T2,      T4, 2.f);
    k_epi1<<<NBK, 256, 0, stream>>>(x, T1, T2, T3, T4, Wx1, bx1, bh1, hb);

    // ---- cell 2: v = hb ----
    k_spmm<<<NBK, 256, 0, stream>>>(off_bk, edges, hb, nullptr, T1, 1.f);
    k_spmm<<<NBK, 256, 0, stream>>>(off_bk, edges, T1, hb,      T2, 2.f);
    k_spmm<<<NBK, 256, 0, stream>>>(off_bk, edges, T2, T1,      T3, 2.f);
    k_spmm<<<NBK, 256, 0, stream>>>(off_bk, edges, T3, T2,      T4, 2.f);
    k_epi2<<<NBK, 256, 0, stream>>>(hb, T1, T2, T3, T4, Wx2, bx2, bh2, Wl, bl, out);
}

// Round 8
// 460.519 us; speedup vs baseline: 6.4977x; 1.0385x over previous
//
#include <hip/hip_runtime.h>
#include <math.h>

#define NN 50000
#define NE 1600000
#define KORD 5
#define NB 196          // ceil(NN/256)
#define QTR 12500       // node quarter (k_deg)
#define GE 782          // epi grid: ceil(NN/64)
#define NBK 1563        // ceil(NN/32) destination buckets (32 nodes each)
#define NBP 1600        // padded bucket stride
#define NCH 128         // chunks for bucket kernels
#define ECH (NE / NCH)  // 12500
#define EC4 (NE / 64)   // 25000 (k_deg chunks)

#define SCALE_W 2097152.0f          // 2^21 spmm fixed point
#define INV_SCALE_W (1.0f / 2097152.0f)
#define SCALE_D 4194304.0f          // 2^22 degree fixed point
#define INV_SCALE_D (1.0f / 4194304.0f)

// ---------------- deg: LDS int-fixed-point weighted row histogram ----------
__global__ __launch_bounds__(1024) void k_deg(const int* __restrict__ ei,
                                              const float* __restrict__ ew,
                                              int* __restrict__ deg_g) {
    __shared__ int h[QTR];   // 50 KB
    int q = blockIdx.x >> 6, ch = blockIdx.x & 63;
    for (int i = threadIdx.x; i < QTR; i += 1024) h[i] = 0;
    __syncthreads();
    int base = ch * EC4, lo = q * QTR;
    for (int e = base + threadIdx.x; e < base + EC4; e += 1024) {
        int li = ei[e] - lo;
        if ((unsigned)li < (unsigned)QTR)
            atomicAdd(&h[li], __float2int_rn(ew[e] * SCALE_D));  // ds_add_u32
    }
    __syncthreads();
    int* outp = deg_g + blockIdx.x * QTR;
    for (int i = threadIdx.x; i < QTR; i += 1024) outp[i] = h[i];
}

__global__ __launch_bounds__(256) void k_dis2(const int* __restrict__ deg_g,
                                              float* __restrict__ dis) {
    int n = blockIdx.x * 256 + threadIdx.x;
    if (n >= NN) return;
    int q = n / QTR, i = n % QTR;
    const int* p = deg_g + (q * 64) * QTR + i;
    int s = 0;
#pragma unroll
    for (int c = 0; c < 64; c++) s += p[c * QTR];
    float d = (float)s * INV_SCALE_D;
    dis[n] = s > 0 ? rsqrtf(fmaxf(d, 1e-30f)) : 0.f;
}

// ---------------- bucket histogram: bh[ch][b] ----------
__global__ __launch_bounds__(1024) void k_bhist(const int* __restrict__ ei,
                                                int* __restrict__ bh) {
    __shared__ int hist[NBK];
    int ch = blockIdx.x;
    for (int i = threadIdx.x; i < NBK; i += 1024) hist[i] = 0;
    __syncthreads();
    const int* cols = ei + NE;
    int base = ch * ECH;
    for (int e = base + threadIdx.x; e < base + ECH; e += 1024)
        atomicAdd(&hist[cols[e] >> 5], 1);
    __syncthreads();
    int* outp = bh + ch * NBP;
    for (int b = threadIdx.x; b < NBK; b += 1024) outp[b] = hist[b];
}

// bucket totals across chunks (zero-pads to NBP for the pair-scan)
__global__ __launch_bounds__(256) void k_btot(const int* __restrict__ bh,
                                              int* __restrict__ tot) {
    int b = blockIdx.x * 256 + threadIdx.x;
    if (b >= NBP) return;
    int s = 0;
    if (b < NBK) {
#pragma unroll 8
        for (int ch = 0; ch < NCH; ch++) s += bh[ch * NBP + b];
    }
    tot[b] = s;
}

// one block: pair-compressed exclusive scan of 1563 totals -> off_bk
__global__ __launch_bounds__(1024) void k_bscan1(const int* __restrict__ tot,
                                                 int* __restrict__ off_bk) {
    __shared__ int s[1024];
    int t = threadIdx.x;
    int a0 = (2 * t < NBP) ? tot[2 * t] : 0;
    int a1 = (2 * t + 1 < NBP) ? tot[2 * t + 1] : 0;
    s[t] = a0 + a1;
    __syncthreads();
    for (int d = 1; d < 1024; d <<= 1) {
        int u = (t >= d) ? s[t - d] : 0;
        __syncthreads();
        s[t] += u;
        __syncthreads();
    }
    int excl = (t == 0) ? 0 : s[t - 1];
    if (2 * t < NBK) off_bk[2 * t] = excl;
    if (2 * t + 1 < NBK) off_bk[2 * t + 1] = excl + a0;
    if (t == 0) off_bk[NBK] = NE;
}

// per-(chunk,bucket) absolute cursors written back into bh
__global__ __launch_bounds__(256) void k_bcur(int* __restrict__ bh,
                                              const int* __restrict__ off_bk) {
    int b = blockIdx.x * 256 + threadIdx.x;
    if (b >= NBK) return;
    int run = off_bk[b];
    for (int ch = 0; ch < NCH; ch++) {
        int v = bh[ch * NBP + b];
        bh[ch * NBP + b] = run;
        run += v;
    }
}

// coarse permute: record = (r | local_c<<16, weight-bits)
__global__ __launch_bounds__(1024) void k_cperm(const int* __restrict__ ei,
                                                const float* __restrict__ ew,
                                                const float* __restrict__ dis,
                                                const int* __restrict__ bh,
                                                int2* __restrict__ edges) {
    __shared__ int cur[NBK];
    int ch = blockIdx.x;
    const int* cp = bh + ch * NBP;
    for (int b = threadIdx.x; b < NBK; b += 1024) cur[b] = cp[b];
    __syncthreads();
    int base = ch * ECH;
    for (int e = base + threadIdx.x; e < base + ECH; e += 1024) {
        int r = ei[e], c = ei[NE + e];
        float w = -dis[r] * ew[e] * dis[c];
        int pos = atomicAdd(&cur[c >> 5], 1);   // ds_add_u32, native
        int packed = (int)((unsigned)r | ((unsigned)(c & 31) << 16));
        edges[pos] = make_int2(packed, __float_as_int(w));
    }
}

// ---------------- spmm: 32-node buckets, int fixed-point LDS atomics --------
// 8 lanes/edge (float4 each); 4 independent edge chains per lane.
__global__ __launch_bounds__(256) void k_spmm(const int* __restrict__ off_bk,
                                              const int2* __restrict__ edges,
                                              const float* __restrict__ vin,
                                              const float* __restrict__ prev,
                                              float* __restrict__ vout,
                                              float scale) {
    __shared__ int acc[32][33];
    int b = blockIdx.x;
    for (int i = threadIdx.x; i < 32 * 33; i += 256) (&acc[0][0])[i] = 0;
    __syncthreads();
    int e0 = off_bk[b], e1 = off_bk[b + 1];
    int group = threadIdx.x >> 3, sub = threadIdx.x & 7;
    const float4* vin4 = (const float4*)vin;
    int i = e0 + group;
    for (; i + 96 < e1; i += 128) {  // 4 chains
        int2 ea = edges[i];
        int2 eb = edges[i + 32];
        int2 ec = edges[i + 64];
        int2 ed = edges[i + 96];
        unsigned ra = (unsigned)ea.x, rb = (unsigned)eb.x;
        unsigned rc = (unsigned)ec.x, rd = (unsigned)ed.x;
        float4 va = vin4[(ra & 0xffffu) * 8 + sub];
        float4 vb = vin4[(rb & 0xffffu) * 8 + sub];
        float4 vc = vin4[(rc & 0xffffu) * 8 + sub];
        float4 vd = vin4[(rd & 0xffffu) * 8 + sub];
        float wa = __int_as_float(ea.y) * SCALE_W;
        float wb = __int_as_float(eb.y) * SCALE_W;
        float wc = __int_as_float(ec.y) * SCALE_W;
        float wd = __int_as_float(ed.y) * SCALE_W;
        int* aa = &acc[ra >> 16][sub * 4];
        int* ab = &acc[rb >> 16][sub * 4];
        int* ac = &acc[rc >> 16][sub * 4];
        int* ad = &acc[rd >> 16][sub * 4];
        atomicAdd(aa + 0, __float2int_rn(wa * va.x));
        atomicAdd(aa + 1, __float2int_rn(wa * va.y));
        atomicAdd(aa + 2, __float2int_rn(wa * va.z));
        atomicAdd(aa + 3, __float2int_rn(wa * va.w));
        atomicAdd(ab + 0, __float2int_rn(wb * vb.x));
        atomicAdd(ab + 1, __float2int_rn(wb * vb.y));
        atomicAdd(ab + 2, __float2int_rn(wb * vb.z));
        atomicAdd(ab + 3, __float2int_rn(wb * vb.w));
        atomicAdd(ac + 0, __float2int_rn(wc * vc.x));
        atomicAdd(ac + 1, __float2int_rn(wc * vc.y));
        atomicAdd(ac + 2, __float2int_rn(wc * vc.z));
        atomicAdd(ac + 3, __float2int_rn(wc * vc.w));
        atomicAdd(ad + 0, __float2int_rn(wd * vd.x));
        atomicAdd(ad + 1, __float2int_rn(wd * vd.y));
        atomicAdd(ad + 2, __float2int_rn(wd * vd.z));
        atomicAdd(ad + 3, __float2int_rn(wd * vd.w));
    }
    for (; i < e1; i += 32) {
        int2 ea = edges[i];
        unsigned ra = (unsigned)ea.x;
        float4 va = vin4[(ra & 0xffffu) * 8 + sub];
        float wa = __int_as_float(ea.y) * SCALE_W;
        int* aa = &acc[ra >> 16][sub * 4];
        atomicAdd(aa + 0, __float2int_rn(wa * va.x));
        atomicAdd(aa + 1, __float2int_rn(wa * va.y));
        atomicAdd(aa + 2, __float2int_rn(wa * va.z));
        atomicAdd(aa + 3, __float2int_rn(wa * va.w));
    }
    __syncthreads();
    float sf = scale * INV_SCALE_W;
    int base = b << 5;
    int nl = threadIdx.x >> 3, s4 = threadIdx.x & 7;
    int n = base + nl;
    if (n < NN) {
        const int* a = &acc[nl][s4 * 4];
        float4 o;
        if (prev) {
            float4 p = ((const float4*)prev)[n * 8 + s4];
            o = make_float4(fmaf(sf, (float)a[0], -p.x),
                            fmaf(sf, (float)a[1], -p.y),
                            fmaf(sf, (float)a[2], -p.z),
                            fmaf(sf, (float)a[3], -p.w));
        } else {
            o = make_float4(sf * (float)a[0], sf * (float)a[1],
                            sf * (float)a[2], sf * (float)a[3]);
        }
        ((float4*)vout)[n * 8 + s4] = o;
    }
}

// ---------------- epi1: LDS-tiled GEMM, 512 threads, 8 waves/block ----------
// thread = (oq in 16: cols 2oq,2oq+1 of z and h) x (nq in 32: nodes nq,nq+32)
__global__ __launch_bounds__(512) void k_epi1(
    const float* __restrict__ x, const float* __restrict__ t1,
    const float* __restrict__ t2, const float* __restrict__ t3,
    const float* __restrict__ t4, const float* __restrict__ Wx1,
    const float* __restrict__ bx1, const float* __restrict__ bh1,
    float* __restrict__ h) {
    __shared__ float T[5][64][33];
    int n0 = blockIdx.x * 64;
    const float* bufs[5] = {x, t1, t2, t3, t4};
    for (int idx = threadIdx.x; idx < 5 * 64 * 8; idx += 512) {
        int b = idx >> 9, rem = idx & 511;
        int r = rem >> 3, c4 = rem & 7;
        int rr = n0 + r; if (rr >= NN) rr = NN - 1;
        float4 v = *(const float4*)(bufs[b] + rr * 32 + c4 * 4);
        float* dst = &T[b][r][c4 * 4];
        dst[0] = v.x; dst[1] = v.y; dst[2] = v.z; dst[3] = v.w;
    }
    __syncthreads();
    int nq = threadIdx.x & 31, oq = threadIdx.x >> 5;
    int ob = oq * 2;
    const float* Wz = Wx1;
    const float* Wh = Wx1 + 2 * KORD * 32 * 32;
    float az_[2][2] = {{0.f}}, ah_[2][2] = {{0.f}};
#pragma unroll
    for (int b = 0; b < 5; b++) {
#pragma unroll 4
        for (int i = 0; i < 32; i++) {
            int kw = b * 1024 + i * 32 + ob;
            float2 wz = *(const float2*)(Wz + kw);
            float2 wh = *(const float2*)(Wh + kw);
            float tx0 = T[b][nq][i];
            float tx1 = T[b][nq + 32][i];
            az_[0][0] = fmaf(tx0, wz.x, az_[0][0]);
            az_[0][1] = fmaf(tx0, wz.y, az_[0][1]);
            ah_[0][0] = fmaf(tx0, wh.x, ah_[0][0]);
            ah_[0][1] = fmaf(tx0, wh.y, ah_[0][1]);
            az_[1][0] = fmaf(tx1, wz.x, az_[1][0]);
            az_[1][1] = fmaf(tx1, wz.y, az_[1][1]);
            ah_[1][0] = fmaf(tx1, wh.x, ah_[1][0]);
            ah_[1][1] = fmaf(tx1, wh.y, ah_[1][1]);
        }
    }
#pragma unroll
    for (int a = 0; a < 2; a++) {
        int n = n0 + nq + 32 * a;
        if (n < NN) {
#pragma unroll
            for (int c = 0; c < 2; c++) {
                int j = ob + c;
                float zz = az_[a][c] + bx1[j] + bh1[j];
                float hh = ah_[a][c] + bx1[64 + j] + bh1[64 + j];
                float z = 1.f / (1.f + __expf(-zz));
                float tt = __expf(-2.f * fabsf(hh));
                float ht = copysignf((1.f - tt) / (1.f + tt), hh);
                h[n * 32 + j] = fmaxf((1.f - z) * ht, 0.f);
            }
        }
    }
}

// ---------------- epi2: LDS-tiled GEMM, 512 threads + final linear ----------
// thread = (oq in 16: z col oq, h col oq) x (nq in 32: nodes nq,nq+32)
__global__ __launch_bounds__(512) void k_epi2(
    const float* __restrict__ hin, const float* __restrict__ t1,
    const float* __restrict__ t2, const float* __restrict__ t3,
    const float* __restrict__ t4, const float* __restrict__ Wx2,
    const float* __restrict__ bx2, const float* __restrict__ bh2,
    const float* __restrict__ Wl, const float* __restrict__ bl,
    float* __restrict__ out) {
    __shared__ float T[5][64][33];
    __shared__ float H2[64][17];
    int n0 = blockIdx.x * 64;
    const float* bufs[5] = {hin, t1, t2, t3, t4};
    for (int idx = threadIdx.x; idx < 5 * 64 * 8; idx += 512) {
        int b = idx >> 9, rem = idx & 511;
        int r = rem >> 3, c4 = rem & 7;
        int rr = n0 + r; if (rr >= NN) rr = NN - 1;
        float4 v = *(const float4*)(bufs[b] + rr * 32 + c4 * 4);
        float* dst = &T[b][r][c4 * 4];
        dst[0] = v.x; dst[1] = v.y; dst[2] = v.z; dst[3] = v.w;
    }
    __syncthreads();
    int nq = threadIdx.x & 31, j = threadIdx.x >> 5;
    const float* Wz = Wx2;
    const float* Wh = Wx2 + 2 * KORD * 32 * 16;
    float az_[2] = {0.f}, ah_[2] = {0.f};
#pragma unroll
    for (int b = 0; b < 5; b++) {
#pragma unroll 4
        for (int i = 0; i < 32; i++) {
            int kw = b * 512 + i * 16 + j;
            float wz0 = Wz[kw], wh0 = Wh[kw];
            float tx0 = T[b][nq][i];
            float tx1 = T[b][nq + 32][i];
            az_[0] = fmaf(tx0, wz0, az_[0]);
            ah_[0] = fmaf(tx0, wh0, ah_[0]);
            az_[1] = fmaf(tx1, wz0, az_[1]);
            ah_[1] = fmaf(tx1, wh0, ah_[1]);
        }
    }
#pragma unroll
    for (int a = 0; a < 2; a++) {
        float zz = az_[a] + bx2[j] + bh2[j];
        float hh = ah_[a] + bx2[32 + j] + bh2[32 + j];
        float z = 1.f / (1.f + __expf(-zz));
        float tt = __expf(-2.f * fabsf(hh));
        float ht = copysignf((1.f - tt) / (1.f + tt), hh);
        H2[nq + 32 * a][j] = fmaxf((1.f - z) * ht, 0.f);
    }
    __syncthreads();
    for (int idx = threadIdx.x; idx < 64 * 12; idx += 512) {
        int n = idx / 12, p = idx % 12;
        int gn = n0 + n;
        if (gn < NN) {
            float o = bl[p];
#pragma unroll
            for (int jj = 0; jj < 16; jj++) o = fmaf(H2[n][jj], Wl[p * 16 + jj], o);
            out[gn * 12 + p] = o;
        }
    }
}

// ---------------- launch ----------------

extern "C" void kernel_launch(void* const* d_in, const int* in_sizes, int n_in,
                              void* d_out, int out_size, void* d_ws, size_t ws_size,
                              hipStream_t stream) {
    const float* x   = (const float*)d_in[0];
    const int*   ei  = (const int*)d_in[1];
    const float* ew  = (const float*)d_in[2];
    const float* Wx1 = (const float*)d_in[3];
    const float* bx1 = (const float*)d_in[4];
    const float* bh1 = (const float*)d_in[6];
    const float* Wx2 = (const float*)d_in[7];
    const float* bx2 = (const float*)d_in[8];
    const float* bh2 = (const float*)d_in[10];
    const float* Wl  = (const float*)d_in[11];
    const float* bl  = (const float*)d_in[12];
    float* out = (float*)d_out;

    float* ws     = (float*)d_ws;
    float* dis    = ws;                         // 50048 floats
    int*   bh     = (int*)(ws + 50048);         // NCH*NBP = 204800 ints
    int*   tot    = bh + NCH * NBP;             // NBP ints
    int*   off_bk = tot + NBP;                  // NBP ints
    int2*  edges  = (int2*)(off_bk + NBP);      // NE int2
    float* T1     = (float*)(edges + NE);       // NN*32 floats each
    float* T2     = T1 + NN * 32;
    float* T3     = T2 + NN * 32;
    float* T4     = T3 + NN * 32;
    float* hb     = T4 + NN * 32;
    int*   deg_g  = (int*)T1;  // 256*QTR ints (T1+T2 region, dead before spmm)

    k_deg  <<<256, 1024, 0, stream>>>(ei, ew, deg_g);
    k_dis2 <<<NB, 256, 0, stream>>>(deg_g, dis);
    k_bhist<<<NCH, 1024, 0, stream>>>(ei, bh);
    k_btot <<<7, 256, 0, stream>>>(bh, tot);
    k_bscan1<<<1, 1024, 0, stream>>>(tot, off_bk);
    k_bcur <<<7, 256, 0, stream>>>(bh, off_bk);
    k_cperm<<<NCH, 1024, 0, stream>>>(ei, ew, dis, bh, edges);

    // ---- cell 1: v = x ----
    k_spmm<<<NBK, 256, 0, stream>>>(off_bk, edges, x,  nullptr, T1, 1.f);
    k_spmm<<<NBK, 256, 0, stream>>>(off_bk, edges, T1, x,       T2, 2.f);
    k_spmm<<<NBK, 256, 0, stream>>>(off_bk, edges, T2, T1,      T3, 2.f);
    k_spmm<<<NBK, 256, 0, stream>>>(off_bk, edges, T3, T2,      T4, 2.f);
    k_epi1<<<GE, 512, 0, stream>>>(x, T1, T2, T3, T4, Wx1, bx1, bh1, hb);

    // ---- cell 2: v = hb ----
    k_spmm<<<NBK, 256, 0, stream>>>(off_bk, edges, hb, nullptr, T1, 1.f);
    k_spmm<<<NBK, 256, 0, stream>>>(off_bk, edges, T1, hb,      T2, 2.f);
    k_spmm<<<NBK, 256, 0, stream>>>(off_bk, edges, T2, T1,      T3, 2.f);
    k_spmm<<<NBK, 256, 0, stream>>>(off_bk, edges, T3, T2,      T4, 2.f);
    k_epi2<<<GE, 512, 0, stream>>>(hb, T1, T2, T3, T4, Wx2, bx2, bh2, Wl, bl, out);
}

// Round 9
// 446.262 us; speedup vs baseline: 6.7053x; 1.0319x over previous
//
#include <hip/hip_runtime.h>
#include <math.h>

#define NN 50000
#define NE 1600000
#define KORD 5
#define NB 196          // ceil(NN/256)
#define QTR 12500       // node quarter (k_deg)
#define GE 782          // epi grid: ceil(NN/64)
#define MT 64           // epi node tile
#define NBK 1563        // ceil(NN/32) destination buckets (32 nodes each)
#define NBP 1600        // padded bucket stride
#define NCH 128         // chunks for bucket kernels
#define ECH (NE / NCH)  // 12500
#define EC4 (NE / 64)   // 25000 (k_deg chunks)

#define SCALE_W 2097152.0f          // 2^21 spmm fixed point
#define INV_SCALE_W (1.0f / 2097152.0f)
#define SCALE_D 4194304.0f          // 2^22 degree fixed point
#define INV_SCALE_D (1.0f / 4194304.0f)

// ---------------- deg: LDS int-fixed-point weighted row histogram ----------
__global__ __launch_bounds__(1024) void k_deg(const int* __restrict__ ei,
                                              const float* __restrict__ ew,
                                              int* __restrict__ deg_g) {
    __shared__ int h[QTR];   // 50 KB
    int q = blockIdx.x >> 6, ch = blockIdx.x & 63;
    for (int i = threadIdx.x; i < QTR; i += 1024) h[i] = 0;
    __syncthreads();
    int base = ch * EC4, lo = q * QTR;
    for (int e = base + threadIdx.x; e < base + EC4; e += 1024) {
        int li = ei[e] - lo;
        if ((unsigned)li < (unsigned)QTR)
            atomicAdd(&h[li], __float2int_rn(ew[e] * SCALE_D));  // ds_add_u32
    }
    __syncthreads();
    int* outp = deg_g + blockIdx.x * QTR;
    for (int i = threadIdx.x; i < QTR; i += 1024) outp[i] = h[i];
}

__global__ __launch_bounds__(256) void k_dis2(const int* __restrict__ deg_g,
                                              float* __restrict__ dis) {
    int n = blockIdx.x * 256 + threadIdx.x;
    if (n >= NN) return;
    int q = n / QTR, i = n % QTR;
    const int* p = deg_g + (q * 64) * QTR + i;
    int s = 0;
#pragma unroll
    for (int c = 0; c < 64; c++) s += p[c * QTR];
    float d = (float)s * INV_SCALE_D;
    dis[n] = s > 0 ? rsqrtf(fmaxf(d, 1e-30f)) : 0.f;
}

// ---------------- bucket histogram: bh[ch][b] ----------
__global__ __launch_bounds__(1024) void k_bhist(const int* __restrict__ ei,
                                                int* __restrict__ bh) {
    __shared__ int hist[NBK];
    int ch = blockIdx.x;
    for (int i = threadIdx.x; i < NBK; i += 1024) hist[i] = 0;
    __syncthreads();
    const int* cols = ei + NE;
    int base = ch * ECH;
    for (int e = base + threadIdx.x; e < base + ECH; e += 1024)
        atomicAdd(&hist[cols[e] >> 5], 1);
    __syncthreads();
    int* outp = bh + ch * NBP;
    for (int b = threadIdx.x; b < NBK; b += 1024) outp[b] = hist[b];
}

// bucket totals across chunks (zero-pads to NBP for the pair-scan)
__global__ __launch_bounds__(256) void k_btot(const int* __restrict__ bh,
                                              int* __restrict__ tot) {
    int b = blockIdx.x * 256 + threadIdx.x;
    if (b >= NBP) return;
    int s = 0;
    if (b < NBK) {
#pragma unroll 8
        for (int ch = 0; ch < NCH; ch++) s += bh[ch * NBP + b];
    }
    tot[b] = s;
}

// one block: pair-compressed exclusive scan of 1563 totals -> off_bk
__global__ __launch_bounds__(1024) void k_bscan1(const int* __restrict__ tot,
                                                 int* __restrict__ off_bk) {
    __shared__ int s[1024];
    int t = threadIdx.x;
    int a0 = (2 * t < NBP) ? tot[2 * t] : 0;
    int a1 = (2 * t + 1 < NBP) ? tot[2 * t + 1] : 0;
    s[t] = a0 + a1;
    __syncthreads();
    for (int d = 1; d < 1024; d <<= 1) {
        int u = (t >= d) ? s[t - d] : 0;
        __syncthreads();
        s[t] += u;
        __syncthreads();
    }
    int excl = (t == 0) ? 0 : s[t - 1];
    if (2 * t < NBK) off_bk[2 * t] = excl;
    if (2 * t + 1 < NBK) off_bk[2 * t + 1] = excl + a0;
    if (t == 0) off_bk[NBK] = NE;
}

// per-(chunk,bucket) absolute cursors written back into bh
__global__ __launch_bounds__(256) void k_bcur(int* __restrict__ bh,
                                              const int* __restrict__ off_bk) {
    int b = blockIdx.x * 256 + threadIdx.x;
    if (b >= NBK) return;
    int run = off_bk[b];
    for (int ch = 0; ch < NCH; ch++) {
        int v = bh[ch * NBP + b];
        bh[ch * NBP + b] = run;
        run += v;
    }
}

// coarse permute: record = (r | local_c<<16, weight-bits)
__global__ __launch_bounds__(1024) void k_cperm(const int* __restrict__ ei,
                                                const float* __restrict__ ew,
                                                const float* __restrict__ dis,
                                                const int* __restrict__ bh,
                                                int2* __restrict__ edges) {
    __shared__ int cur[NBK];
    int ch = blockIdx.x;
    const int* cp = bh + ch * NBP;
    for (int b = threadIdx.x; b < NBK; b += 1024) cur[b] = cp[b];
    __syncthreads();
    int base = ch * ECH;
    for (int e = base + threadIdx.x; e < base + ECH; e += 1024) {
        int r = ei[e], c = ei[NE + e];
        float w = -dis[r] * ew[e] * dis[c];
        int pos = atomicAdd(&cur[c >> 5], 1);   // ds_add_u32, native
        int packed = (int)((unsigned)r | ((unsigned)(c & 31) << 16));
        edges[pos] = make_int2(packed, __float_as_int(w));
    }
}

// ---------------- per-bucket exact counting sort by local dest ----------
// Perf-only (spmm is order-agnostic). edges -> edges2, dense L2 traffic.
__global__ __launch_bounds__(256) void k_sort(const int* __restrict__ off_bk,
                                              const int2* __restrict__ edges,
                                              int2* __restrict__ edges2) {
    __shared__ int cnt[32];
    __shared__ int cur[32];
    int b = blockIdx.x;
    int e0 = off_bk[b], e1 = off_bk[b + 1];
    if (threadIdx.x < 32) cnt[threadIdx.x] = 0;
    __syncthreads();
    for (int i = e0 + threadIdx.x; i < e1; i += 256)
        atomicAdd(&cnt[edges[i].x >> 16], 1);
    __syncthreads();
    if (threadIdx.x == 0) {
        int run = e0;
#pragma unroll
        for (int k = 0; k < 32; k++) { cur[k] = run; run += cnt[k]; }
    }
    __syncthreads();
    for (int i = e0 + threadIdx.x; i < e1; i += 256) {
        int2 e = edges[i];
        int p = atomicAdd(&cur[e.x >> 16], 1);
        edges2[p] = e;
    }
}

// ---------------- spmm: sorted strips + register run-accumulation ----------
// 32 strips/block x 8 subs (float4). Register acc flushed to LDS (int
// fixed-point ds_add) only on dest-change / strip end: ~2 flushes/strip.
__global__ __launch_bounds__(256) void k_spmm(const int* __restrict__ off_bk,
                                              const int2* __restrict__ edges,
                                              const float* __restrict__ vin,
                                              const float* __restrict__ prev,
                                              float* __restrict__ vout,
                                              float scale) {
    __shared__ int acc[32][33];
    int b = blockIdx.x;
    for (int i = threadIdx.x; i < 32 * 33; i += 256) (&acc[0][0])[i] = 0;
    __syncthreads();
    int e0 = off_bk[b], e1 = off_bk[b + 1];
    int len = e1 - e0;
    int g = threadIdx.x >> 3, sub = threadIdx.x & 7;
    int S = (len + 31) >> 5;
    int i = e0 + g * S;
    int sEnd = i + S; if (sEnd > e1) sEnd = e1;
    const float4* vin4 = (const float4*)vin;
    if (i < sEnd && len > 0) {
        int2 e = edges[i];
        int curc = e.x >> 16;
        float ax = 0.f, ay = 0.f, az = 0.f, aw = 0.f;
        while (true) {
            bool more = (i + 1 < sEnd);
            int2 en;
            if (more) en = edges[i + 1];           // prefetch next edge
            float w = __int_as_float(e.y);
            float4 v = vin4[(e.x & 0xffff) * 8 + sub];
            ax = fmaf(w, v.x, ax); ay = fmaf(w, v.y, ay);
            az = fmaf(w, v.z, az); aw = fmaf(w, v.w, aw);
            if (!more) break;
            i++;
            int c2 = en.x >> 16;
            if (c2 != curc) {
                int* a = &acc[curc][sub * 4];
                atomicAdd(a + 0, __float2int_rn(ax * SCALE_W));
                atomicAdd(a + 1, __float2int_rn(ay * SCALE_W));
                atomicAdd(a + 2, __float2int_rn(az * SCALE_W));
                atomicAdd(a + 3, __float2int_rn(aw * SCALE_W));
                ax = 0.f; ay = 0.f; az = 0.f; aw = 0.f;
                curc = c2;
            }
            e = en;
        }
        int* a = &acc[curc][sub * 4];
        atomicAdd(a + 0, __float2int_rn(ax * SCALE_W));
        atomicAdd(a + 1, __float2int_rn(ay * SCALE_W));
        atomicAdd(a + 2, __float2int_rn(az * SCALE_W));
        atomicAdd(a + 3, __float2int_rn(aw * SCALE_W));
    }
    __syncthreads();
    float sf = scale * INV_SCALE_W;
    int base = b << 5;
    int nl = threadIdx.x >> 3, s4 = threadIdx.x & 7;
    int n = base + nl;
    if (n < NN) {
        const int* a = &acc[nl][s4 * 4];
        float4 o;
        if (prev) {
            float4 p = ((const float4*)prev)[n * 8 + s4];
            o = make_float4(fmaf(sf, (float)a[0], -p.x),
                            fmaf(sf, (float)a[1], -p.y),
                            fmaf(sf, (float)a[2], -p.z),
                            fmaf(sf, (float)a[3], -p.w));
        } else {
            o = make_float4(sf * (float)a[0], sf * (float)a[1],
                            sf * (float)a[2], sf * (float)a[3]);
        }
        ((float4*)vout)[n * 8 + s4] = o;
    }
}

// ---------------- epi1: LDS-tiled GEMM (K=160 -> 32z+32h) + GRU fuse --------
// thread = (nq in 16, oq in 16): 4 nodes (stride 16) x 2 z-cols + 2 h-cols.
__global__ __launch_bounds__(256) void k_epi1(
    const float* __restrict__ x, const float* __restrict__ t1,
    const float* __restrict__ t2, const float* __restrict__ t3,
    const float* __restrict__ t4, const float* __restrict__ Wx1,
    const float* __restrict__ bx1, const float* __restrict__ bh1,
    float* __restrict__ h) {
    __shared__ float T[5][MT][33];
    int n0 = blockIdx.x * MT;
    const float* bufs[5] = {x, t1, t2, t3, t4};
#pragma unroll
    for (int b = 0; b < 5; b++) {
        for (int idx = threadIdx.x; idx < MT * 8; idx += 256) {
            int r = idx >> 3, c4 = idx & 7;
            int rr = n0 + r; if (rr >= NN) rr = NN - 1;
            float4 v = *(const float4*)(bufs[b] + rr * 32 + c4 * 4);
            float* dst = &T[b][r][c4 * 4];
            dst[0] = v.x; dst[1] = v.y; dst[2] = v.z; dst[3] = v.w;
        }
    }
    __syncthreads();
    int nq = threadIdx.x & 15, oq = threadIdx.x >> 4;
    int ob = oq * 2;
    const float* Wz = Wx1;
    const float* Wh = Wx1 + 2 * KORD * 32 * 32;
    float az_[4][2] = {{0.f}}, ah_[4][2] = {{0.f}};
#pragma unroll
    for (int b = 0; b < 5; b++) {
#pragma unroll 4
        for (int i = 0; i < 32; i++) {
            int kw = b * 1024 + i * 32 + ob;
            float wz0 = Wz[kw], wz1 = Wz[kw + 1];
            float wh0 = Wh[kw], wh1 = Wh[kw + 1];
#pragma unroll
            for (int a = 0; a < 4; a++) {
                float tx = T[b][nq + 16 * a][i];
                az_[a][0] = fmaf(tx, wz0, az_[a][0]);
                az_[a][1] = fmaf(tx, wz1, az_[a][1]);
                ah_[a][0] = fmaf(tx, wh0, ah_[a][0]);
                ah_[a][1] = fmaf(tx, wh1, ah_[a][1]);
            }
        }
    }
#pragma unroll
    for (int a = 0; a < 4; a++) {
        int n = n0 + nq + 16 * a;
        if (n < NN) {
#pragma unroll
            for (int c = 0; c < 2; c++) {
                int j = ob + c;
                float zz = az_[a][c] + bx1[j] + bh1[j];
                float hh = ah_[a][c] + bx1[64 + j] + bh1[64 + j];
                float z = 1.f / (1.f + __expf(-zz));
                float tt = __expf(-2.f * fabsf(hh));
                float ht = copysignf((1.f - tt) / (1.f + tt), hh);
                h[n * 32 + j] = fmaxf((1.f - z) * ht, 0.f);
            }
        }
    }
}

// ---------------- epi2: LDS-tiled GEMM (K=160 -> 16z+16h) + final linear ----
__global__ __launch_bounds__(256) void k_epi2(
    const float* __restrict__ hin, const float* __restrict__ t1,
    const float* __restrict__ t2, const float* __restrict__ t3,
    const float* __restrict__ t4, const float* __restrict__ Wx2,
    const float* __restrict__ bx2, const float* __restrict__ bh2,
    const float* __restrict__ Wl, const float* __restrict__ bl,
    float* __restrict__ out) {
    __shared__ float T[5][MT][33];
    __shared__ float H2[MT][17];
    int n0 = blockIdx.x * MT;
    const float* bufs[5] = {hin, t1, t2, t3, t4};
#pragma unroll
    for (int b = 0; b < 5; b++) {
        for (int idx = threadIdx.x; idx < MT * 8; idx += 256) {
            int r = idx >> 3, c4 = idx & 7;
            int rr = n0 + r; if (rr >= NN) rr = NN - 1;
            float4 v = *(const float4*)(bufs[b] + rr * 32 + c4 * 4);
            float* dst = &T[b][r][c4 * 4];
            dst[0] = v.x; dst[1] = v.y; dst[2] = v.z; dst[3] = v.w;
        }
    }
    __syncthreads();
    int nq = threadIdx.x & 15, j = threadIdx.x >> 4;
    const float* Wz = Wx2;
    const float* Wh = Wx2 + 2 * KORD * 32 * 16;
    float az_[4] = {0.f}, ah_[4] = {0.f};
#pragma unroll
    for (int b = 0; b < 5; b++) {
#pragma unroll 4
        for (int i = 0; i < 32; i++) {
            int kw = b * 512 + i * 16 + j;
            float wz0 = Wz[kw], wh0 = Wh[kw];
#pragma unroll
            for (int a = 0; a < 4; a++) {
                float tx = T[b][nq + 16 * a][i];
                az_[a] = fmaf(tx, wz0, az_[a]);
                ah_[a] = fmaf(tx, wh0, ah_[a]);
            }
        }
    }
#pragma unroll
    for (int a = 0; a < 4; a++) {
        float zz = az_[a] + bx2[j] + bh2[j];
        float hh = ah_[a] + bx2[32 + j] + bh2[32 + j];
        float z = 1.f / (1.f + __expf(-zz));
        float tt = __expf(-2.f * fabsf(hh));
        float ht = copysignf((1.f - tt) / (1.f + tt), hh);
        H2[nq + 16 * a][j] = fmaxf((1.f - z) * ht, 0.f);
    }
    __syncthreads();
    for (int idx = threadIdx.x; idx < MT * 12; idx += 256) {
        int n = idx / 12, p = idx % 12;
        int gn = n0 + n;
        if (gn < NN) {
            float o = bl[p];
#pragma unroll
            for (int jj = 0; jj < 16; jj++) o = fmaf(H2[n][jj], Wl[p * 16 + jj], o);
            out[gn * 12 + p] = o;
        }
    }
}

// ---------------- launch ----------------

extern "C" void kernel_launch(void* const* d_in, const int* in_sizes, int n_in,
                              void* d_out, int out_size, void* d_ws, size_t ws_size,
                              hipStream_t stream) {
    const float* x   = (const float*)d_in[0];
    const int*   ei  = (const int*)d_in[1];
    const float* ew  = (const float*)d_in[2];
    const float* Wx1 = (const float*)d_in[3];
    const float* bx1 = (const float*)d_in[4];
    const float* bh1 = (const float*)d_in[6];
    const float* Wx2 = (const float*)d_in[7];
    const float* bx2 = (const float*)d_in[8];
    const float* bh2 = (const float*)d_in[10];
    const float* Wl  = (const float*)d_in[11];
    const float* bl  = (const float*)d_in[12];
    float* out = (float*)d_out;

    float* ws     = (float*)d_ws;
    float* dis    = ws;                         // 50048 floats
    int*   bh     = (int*)(ws + 50048);         // NCH*NBP ints
    int*   tot    = bh + NCH * NBP;             // NBP ints
    int*   off_bk = tot + NBP;                  // NBP ints
    int2*  edges  = (int2*)(off_bk + NBP);      // NE int2 (coarse)
    int2*  edges2 = edges + NE;                 // NE int2 (exact-sorted)
    float* T1     = (float*)(edges2 + NE);      // NN*32 floats each
    float* T2     = T1 + NN * 32;
    float* T3     = T2 + NN * 32;
    float* T4     = T3 + NN * 32;
    float* hb     = T4 + NN * 32;
    int*   deg_g  = (int*)T1;  // 256*QTR ints (T1+T2 region, dead before spmm)

    k_deg  <<<256, 1024, 0, stream>>>(ei, ew, deg_g);
    k_dis2 <<<NB, 256, 0, stream>>>(deg_g, dis);
    k_bhist<<<NCH, 1024, 0, stream>>>(ei, bh);
    k_btot <<<7, 256, 0, stream>>>(bh, tot);
    k_bscan1<<<1, 1024, 0, stream>>>(tot, off_bk);
    k_bcur <<<7, 256, 0, stream>>>(bh, off_bk);
    k_cperm<<<NCH, 1024, 0, stream>>>(ei, ew, dis, bh, edges);
    k_sort <<<NBK, 256, 0, stream>>>(off_bk, edges, edges2);

    // ---- cell 1: v = x ----
    k_spmm<<<NBK, 256, 0, stream>>>(off_bk, edges2, x,  nullptr, T1, 1.f);
    k_spmm<<<NBK, 256, 0, stream>>>(off_bk, edges2, T1, x,       T2, 2.f);
    k_spmm<<<NBK, 256, 0, stream>>>(off_bk, edges2, T2, T1,      T3, 2.f);
    k_spmm<<<NBK, 256, 0, stream>>>(off_bk, edges2, T3, T2,      T4, 2.f);
    k_epi1<<<GE, 256, 0, stream>>>(x, T1, T2, T3, T4, Wx1, bx1, bh1, hb);

    // ---- cell 2: v = hb ----
    k_spmm<<<NBK, 256, 0, stream>>>(off_bk, edges2, hb, nullptr, T1, 1.f);
    k_spmm<<<NBK, 256, 0, stream>>>(off_bk, edges2, T1, hb,      T2, 2.f);
    k_spmm<<<NBK, 256, 0, stream>>>(off_bk, edges2, T2, T1,      T3, 2.f);
    k_spmm<<<NBK, 256, 0, stream>>>(off_bk, edges2, T3, T2,      T4, 2.f);
    k_epi2<<<GE, 256, 0, stream>>>(hb, T1, T2, T3, T4, Wx2, bx2, bh2, Wl, bl, out);
}